// Round 4
// baseline (582.479 us; speedup 1.0000x reference)
//
#include <hip/hip_runtime.h>
#include <hip/hip_bf16.h>
#include <stdint.h>

typedef float  f32x16 __attribute__((ext_vector_type(16)));
typedef __bf16 bf16x8 __attribute__((ext_vector_type(8)));
typedef unsigned u32x4 __attribute__((ext_vector_type(4)));

#define NH 1280
#define KBLKS 80
#define MAT_ELEMS (KBLKS * NH * 16)    // u16 elems per 1280x1280 matrix

// workspace offsets (bytes)
#define OFF_W1S  0u
#define OFF_W2S  6553600u
#define OFF_W3S  9830400u
#define OFF_HI   13107200u
#define OFF_HJB  18350080u
#define OFF_H2   23592960u   // 1024 tiles * 163840 B

__device__ __forceinline__ unsigned short bfb(float f) {
    unsigned u = __builtin_bit_cast(unsigned, f);
    u += 0x7fffu + ((u >> 16) & 1u);          // RNE
    return (unsigned short)(u >> 16);
}
__device__ __forceinline__ unsigned pk2(float lo, float hi) {
    return (unsigned)bfb(lo) | ((unsigned)bfb(hi) << 16);
}

// ---------------------------------------------------------------------------
// k_cvt: f32 row-major -> bf16 MFMA-B fragment-linear (unchanged, verified).
// ---------------------------------------------------------------------------
__global__ void k_cvt(const float* __restrict__ src, unsigned short* __restrict__ dst) {
    __shared__ float tile[16][257];
    const int kb = blockIdx.x, cb = blockIdx.y, t = threadIdx.x;
#pragma unroll
    for (int r = 0; r < 16; ++r)
        tile[r][t] = src[(size_t)(kb * 16 + r) * NH + cb * 256 + t];
    __syncthreads();
    const int col = cb * 256 + t;
    unsigned u[8];
#pragma unroll
    for (int i = 0; i < 8; ++i) u[i] = pk2(tile[2 * i][t], tile[2 * i + 1][t]);
    u32x4* d = (u32x4*)(dst + ((size_t)kb * NH + col) * 16);
    u32x4 w0 = {u[0], u[1], u[2], u[3]}, w1 = {u[4], u[5], u[6], u[7]};
    d[0] = w0; d[1] = w1;
}

// ---------------------------------------------------------------------------
// Stagers: fill one 80KB half-tile (64 rows x 640 bf16 cols, rowstride 1280B,
// XOR-swizzled) in 10 chunks/thread. Two reg sets (A/B) for the sync stage;
// set A alone is used for the interleaved (async) stage.
// ---------------------------------------------------------------------------
struct StgG1 {   // h1 = relu(Hi[row] + Hj) -> bf16
    const float* Hi; const float* Hj; char* dst; int cb; int tid;
    float4 xa0, xa1, xj0, xj1, ya0, ya1, yj0, yj1;
    __device__ __forceinline__ void ldA(int q) {
        if (q >= 10) return; int cid = tid + (q << 9);
        int row = cid / 80, c8 = (cid - row * 80) << 3, col = cb + c8;
        const float* r = Hi + row * NH + col;
        xa0 = *(const float4*)r; xa1 = *(const float4*)(r + 4);
        xj0 = *(const float4*)(Hj + col); xj1 = *(const float4*)(Hj + col + 4);
    }
    __device__ __forceinline__ void cmA(int q) {
        if (q >= 10) return; int cid = tid + (q << 9);
        int row = cid / 80, c8 = (cid - row * 80) << 3;
        uint4 pk;
        pk.x = pk2(fmaxf(xa0.x + xj0.x, 0.f), fmaxf(xa0.y + xj0.y, 0.f));
        pk.y = pk2(fmaxf(xa0.z + xj0.z, 0.f), fmaxf(xa0.w + xj0.w, 0.f));
        pk.z = pk2(fmaxf(xa1.x + xj1.x, 0.f), fmaxf(xa1.y + xj1.y, 0.f));
        pk.w = pk2(fmaxf(xa1.z + xj1.z, 0.f), fmaxf(xa1.w + xj1.w, 0.f));
        *(uint4*)(dst + row * 1280 + ((unsigned)(c8 << 1) ^ ((unsigned)(row & 7) << 4))) = pk;
    }
    __device__ __forceinline__ void ldB(int q) {
        if (q >= 10) return; int cid = tid + (q << 9);
        int row = cid / 80, c8 = (cid - row * 80) << 3, col = cb + c8;
        const float* r = Hi + row * NH + col;
        ya0 = *(const float4*)r; ya1 = *(const float4*)(r + 4);
        yj0 = *(const float4*)(Hj + col); yj1 = *(const float4*)(Hj + col + 4);
    }
    __device__ __forceinline__ void cmB(int q) {
        if (q >= 10) return; int cid = tid + (q << 9);
        int row = cid / 80, c8 = (cid - row * 80) << 3;
        uint4 pk;
        pk.x = pk2(fmaxf(ya0.x + yj0.x, 0.f), fmaxf(ya0.y + yj0.y, 0.f));
        pk.y = pk2(fmaxf(ya0.z + yj0.z, 0.f), fmaxf(ya0.w + yj0.w, 0.f));
        pk.z = pk2(fmaxf(ya1.x + yj1.x, 0.f), fmaxf(ya1.y + yj1.y, 0.f));
        pk.w = pk2(fmaxf(ya1.z + yj1.z, 0.f), fmaxf(ya1.w + yj1.w, 0.f));
        *(uint4*)(dst + row * 1280 + ((unsigned)(c8 << 1) ^ ((unsigned)(row & 7) << 4))) = pk;
    }
};

struct StgHJ {   // roi f32 -> bf16 (no add, no relu)
    const float* Hi; char* dst; int cb; int tid;
    float4 xa0, xa1, ya0, ya1;
    __device__ __forceinline__ void ldA(int q) {
        if (q >= 10) return; int cid = tid + (q << 9);
        int row = cid / 80, c8 = (cid - row * 80) << 3, col = cb + c8;
        const float* r = Hi + row * NH + col;
        xa0 = *(const float4*)r; xa1 = *(const float4*)(r + 4);
    }
    __device__ __forceinline__ void cmA(int q) {
        if (q >= 10) return; int cid = tid + (q << 9);
        int row = cid / 80, c8 = (cid - row * 80) << 3;
        uint4 pk;
        pk.x = pk2(xa0.x, xa0.y); pk.y = pk2(xa0.z, xa0.w);
        pk.z = pk2(xa1.x, xa1.y); pk.w = pk2(xa1.z, xa1.w);
        *(uint4*)(dst + row * 1280 + ((unsigned)(c8 << 1) ^ ((unsigned)(row & 7) << 4))) = pk;
    }
    __device__ __forceinline__ void ldB(int q) {
        if (q >= 10) return; int cid = tid + (q << 9);
        int row = cid / 80, c8 = (cid - row * 80) << 3, col = cb + c8;
        const float* r = Hi + row * NH + col;
        ya0 = *(const float4*)r; ya1 = *(const float4*)(r + 4);
    }
    __device__ __forceinline__ void cmB(int q) {
        if (q >= 10) return; int cid = tid + (q << 9);
        int row = cid / 80, c8 = (cid - row * 80) << 3;
        uint4 pk;
        pk.x = pk2(ya0.x, ya0.y); pk.y = pk2(ya0.z, ya0.w);
        pk.z = pk2(ya1.x, ya1.y); pk.w = pk2(ya1.z, ya1.w);
        *(uint4*)(dst + row * 1280 + ((unsigned)(c8 << 1) ^ ((unsigned)(row & 7) << 4))) = pk;
    }
};

struct StgG2 {   // raw 16B copy of pre-swizzled h2 image
    const u32x4* src; char* dst; int tid;
    u32x4 ua, ub;
    __device__ __forceinline__ void ldA(int q) {
        if (q >= 10) return; ua = __builtin_nontemporal_load(src + tid + (q << 9));
    }
    __device__ __forceinline__ void cmA(int q) {
        if (q >= 10) return; *(u32x4*)(dst + ((size_t)(tid + (q << 9)) << 4)) = ua;
    }
    __device__ __forceinline__ void ldB(int q) {
        if (q >= 10) return; ub = __builtin_nontemporal_load(src + tid + (q << 9));
    }
    __device__ __forceinline__ void cmB(int q) {
        if (q >= 10) return; *(u32x4*)(dst + ((size_t)(tid + (q << 9)) << 4)) = ub;
    }
};

template<class S>
__device__ __forceinline__ void sync_stage(S& s) {
    s.ldA(0); s.ldB(1);
    for (int q = 0; q < 10; q += 2) { s.cmA(q); s.ldA(q + 2); s.cmB(q + 1); s.ldB(q + 3); }
}

// ---------------------------------------------------------------------------
// One K-half (40 kblks) of: C(64x160/wave) += A(LDS half, swizzled) @ B(frag-
// linear global). 4-deep B prefetch (static buffers). If STG, interleaves 10
// async stage-chunks (1 per 4 kblks) building the other LDS half.
// Over-prefetch past the half end is harmless (stays inside ws).
// ---------------------------------------------------------------------------
template<bool STG, class S>
__device__ __forceinline__ void gemm_half(const char* a0p, const char* a1p, unsigned xr,
                                          unsigned hsel16, const char* bph,
                                          f32x16 acc[2][5], S& s) {
    bf16x8 B0[5], B1[5], B2[5], B3[5];
#define LDBH(D_, KH_) { _Pragma("unroll") for (int cf = 0; cf < 5; ++cf) \
    D_[cf] = __builtin_bit_cast(bf16x8, *(const uint4*)(bph + (size_t)(KH_) * 40960 + cf * 1024)); }
    LDBH(B0, 0) LDBH(B1, 1) LDBH(B2, 2) LDBH(B3, 3)
    for (int kq = 0; kq < 10; ++kq) {
        if constexpr (STG) { s.cmA(kq); s.ldA(kq + 1); }
        const int k0 = kq * 4;
#define STEP(KH_, B_) { unsigned ko = (((unsigned)(KH_)) * 32u + hsel16) ^ xr; \
        bf16x8 a0 = __builtin_bit_cast(bf16x8, *(const uint4*)(a0p + ko)); \
        bf16x8 a1 = __builtin_bit_cast(bf16x8, *(const uint4*)(a1p + ko)); \
        _Pragma("unroll") for (int cf = 0; cf < 5; ++cf) { \
            acc[0][cf] = __builtin_amdgcn_mfma_f32_32x32x16_bf16(a0, B_[cf], acc[0][cf], 0, 0, 0); \
            acc[1][cf] = __builtin_amdgcn_mfma_f32_32x32x16_bf16(a1, B_[cf], acc[1][cf], 0, 0, 0); } \
        LDBH(B_, (KH_) + 4) }
        STEP(k0 + 0, B0) STEP(k0 + 1, B1) STEP(k0 + 2, B2) STEP(k0 + 3, B3)
#undef STEP
    }
#undef LDBH
}

__device__ __forceinline__ void zero_acc(f32x16 acc[2][5]) {
#pragma unroll
    for (int rf = 0; rf < 2; ++rf)
#pragma unroll
        for (int cf = 0; cf < 5; ++cf)
#pragma unroll
            for (int i = 0; i < 16; ++i) acc[rf][cf][i] = 0.f;
}

// ---------------------------------------------------------------------------
// k_hihj: Hi = roi@W1[:C]; Hjb = roi@W1[C:] + b1   (32 WGs; small)
// ---------------------------------------------------------------------------
__global__ __launch_bounds__(512, 2) void k_hihj(const float* __restrict__ roi, const float* __restrict__ b1,
                                                 const unsigned short* __restrict__ w1s,
                                                 float* __restrict__ Hi, float* __restrict__ Hjb) {
    __shared__ __align__(16) char lds[163840];
    char* buf0 = lds; char* buf1 = lds + 81920;
    const int b = blockIdx.x >> 1, hh = blockIdx.x & 1, tid = threadIdx.x;
    StgHJ s; s.Hi = roi + (size_t)b * 64 * NH; s.dst = buf0; s.cb = 0; s.tid = tid;
    sync_stage(s);
    s.dst = buf1; s.cb = 640;
    s.ldA(0);
    __syncthreads();
    const int wave = tid >> 6, lane = tid & 63, rlo = lane & 31, hsel = lane >> 5;
    const int colbase = wave * 160;
    const unsigned xr = (unsigned)(rlo & 7) << 4, h16 = (unsigned)hsel * 16u;
    const char* a0 = buf0 + rlo * 1280;
    const char* bp = (const char*)(w1s + (size_t)hh * MAT_ELEMS) + (size_t)(colbase + rlo) * 32 + (size_t)hsel * 16;
    f32x16 acc[2][5]; zero_acc(acc);
    gemm_half<true>(a0, a0 + 40960, xr, h16, bp, acc, s);
    __syncthreads();
    const char* a0b = buf1 + rlo * 1280;
    gemm_half<false>(a0b, a0b + 40960, xr, h16, bp + (size_t)40 * 40960, acc, s);
    float bias[5];
#pragma unroll
    for (int cf = 0; cf < 5; ++cf) bias[cf] = hh ? b1[colbase + cf * 32 + rlo] : 0.f;
    float* dst = hh ? Hjb : Hi;
#pragma unroll
    for (int rf = 0; rf < 2; ++rf)
#pragma unroll
        for (int cf = 0; cf < 5; ++cf) {
            int col = colbase + cf * 32 + rlo;
#pragma unroll
            for (int j = 0; j < 16; ++j) {
                int row = rf * 32 + (j & 3) + ((j >> 2) << 3) + (hsel << 2);
                dst[(size_t)(b * 64 + row) * NH + col] = acc[rf][cf][j] + bias[cf];
            }
        }
}

// ---------------------------------------------------------------------------
// k_g1: h1 = relu(Hi+Hj) (K-phased async staging); h2 = relu(h1@W2+b2) ->
// two 80KB half-images -> NT store to ws.
// ---------------------------------------------------------------------------
__global__ __launch_bounds__(512, 2) void k_g1(const float* __restrict__ Hi, const float* __restrict__ Hjb,
                                               const float* __restrict__ b2,
                                               const unsigned short* __restrict__ w2s,
                                               char* __restrict__ h2g) {
    __shared__ __align__(16) char lds[163840];
    char* buf0 = lds; char* buf1 = lds + 81920;
    const int bn = blockIdx.x, b = bn >> 6, n = bn & 63, tid = threadIdx.x;
    StgG1 s; s.Hi = Hi + (size_t)b * 64 * NH; s.Hj = Hjb + (size_t)(b * 64 + n) * NH;
    s.dst = buf0; s.cb = 0; s.tid = tid;
    sync_stage(s);
    s.dst = buf1; s.cb = 640;
    s.ldA(0);                              // pre-issue chunk 0 of half 1
    __syncthreads();
    const int wave = tid >> 6, lane = tid & 63, rlo = lane & 31, hsel = lane >> 5;
    const int colbase = wave * 160;
    const unsigned xr = (unsigned)(rlo & 7) << 4, h16 = (unsigned)hsel * 16u;
    const char* a0 = buf0 + rlo * 1280;
    const char* bp = (const char*)w2s + (size_t)(colbase + rlo) * 32 + (size_t)hsel * 16;
    f32x16 acc[2][5]; zero_acc(acc);
    gemm_half<true>(a0, a0 + 40960, xr, h16, bp, acc, s);
    __syncthreads();                       // buf1 complete
    const char* a0b = buf1 + rlo * 1280;
    gemm_half<false>(a0b, a0b + 40960, xr, h16, bp + (size_t)40 * 40960, acc, s);
    __syncthreads();                       // all reads of buf0/buf1 done
    float bv[5];
#pragma unroll
    for (int cf = 0; cf < 5; ++cf) bv[cf] = b2[colbase + cf * 32 + rlo];
    char* ibuf = (wave < 4) ? buf0 : buf1;
    const int cb2 = (wave < 4) ? colbase : colbase - 640;
#pragma unroll
    for (int rf = 0; rf < 2; ++rf)
#pragma unroll
        for (int cf = 0; cf < 5; ++cf) {
            int colloc = cb2 + cf * 32 + rlo;
#pragma unroll
            for (int j = 0; j < 16; ++j) {
                int row = rf * 32 + (j & 3) + ((j >> 2) << 3) + (hsel << 2);
                float v = fmaxf(acc[rf][cf][j] + bv[cf], 0.f);
                *(unsigned short*)(ibuf + row * 1280 +
                    ((unsigned)(colloc << 1) ^ ((unsigned)(row & 7) << 4))) = bfb(v);
            }
        }
    __syncthreads();
    u32x4* dstg = (u32x4*)(h2g + (size_t)bn * 163840);
    const u32x4* ls = (const u32x4*)lds;
    for (int q = 0; q < 20; ++q) {
        int idx = tid + (q << 9);
        __builtin_nontemporal_store(ls[idx], dstg + idx);
    }
}

// ---------------------------------------------------------------------------
// k_g2: load h2 half-images (async-staged), h3 = relu(h2@W3+b3), row-reduce,
// atomicAdd into out.
// ---------------------------------------------------------------------------
__global__ __launch_bounds__(512, 2) void k_g2(const char* __restrict__ h2g,
                                               const float* __restrict__ b3,
                                               const unsigned short* __restrict__ w3s,
                                               float* __restrict__ out) {
    __shared__ __align__(16) char lds[163840];
    char* buf0 = lds; char* buf1 = lds + 81920;
    const int bn = blockIdx.x, b = bn >> 6, tid = threadIdx.x;
    StgG2 s; s.src = (const u32x4*)(h2g + (size_t)bn * 163840); s.dst = buf0; s.tid = tid;
    sync_stage(s);
    s.src += 5120; s.dst = buf1;
    s.ldA(0);
    __syncthreads();
    const int wave = tid >> 6, lane = tid & 63, rlo = lane & 31, hsel = lane >> 5;
    const int colbase = wave * 160;
    const unsigned xr = (unsigned)(rlo & 7) << 4, h16 = (unsigned)hsel * 16u;
    const char* a0 = buf0 + rlo * 1280;
    const char* bp = (const char*)w3s + (size_t)(colbase + rlo) * 32 + (size_t)hsel * 16;
    f32x16 acc[2][5]; zero_acc(acc);
    gemm_half<true>(a0, a0 + 40960, xr, h16, bp, acc, s);
    __syncthreads();
    const char* a0b = buf1 + rlo * 1280;
    gemm_half<false>(a0b, a0b + 40960, xr, h16, bp + (size_t)40 * 40960, acc, s);
    float b3v[5];
#pragma unroll
    for (int cf = 0; cf < 5; ++cf) b3v[cf] = b3[colbase + cf * 32 + rlo];
#pragma unroll
    for (int cf = 0; cf < 5; ++cf) {
        float sum = 0.f;
#pragma unroll
        for (int rf = 0; rf < 2; ++rf)
#pragma unroll
            for (int j = 0; j < 16; ++j) sum += fmaxf(acc[rf][cf][j] + b3v[cf], 0.f);
        sum += __shfl_xor(sum, 32);
        if (lane < 32) atomicAdd(out + b * NH + colbase + cf * 32 + lane, sum);
    }
}

extern "C" void kernel_launch(void* const* d_in, const int* in_sizes, int n_in,
                              void* d_out, int out_size, void* d_ws, size_t ws_size,
                              hipStream_t stream) {
    const float* roi = (const float*)d_in[0];
    const float* W1  = (const float*)d_in[1];
    const float* b1  = (const float*)d_in[2];
    const float* W2  = (const float*)d_in[3];
    const float* b2  = (const float*)d_in[4];
    const float* W3  = (const float*)d_in[5];
    const float* b3  = (const float*)d_in[6];
    float* out = (float*)d_out;
    char* ws = (char*)d_ws;
    unsigned short* w1s = (unsigned short*)(ws + OFF_W1S);
    unsigned short* w2s = (unsigned short*)(ws + OFF_W2S);
    unsigned short* w3s = (unsigned short*)(ws + OFF_W3S);
    float* Hi  = (float*)(ws + OFF_HI);
    float* Hjb = (float*)(ws + OFF_HJB);
    char*  h2g = ws + OFF_H2;

    (void)hipMemsetAsync(out, 0, (size_t)16 * NH * sizeof(float), stream);

    k_cvt<<<dim3(80, 5), 256, 0, stream>>>(W1, w1s);
    k_cvt<<<dim3(80, 5), 256, 0, stream>>>(W1 + (size_t)NH * NH, w1s + MAT_ELEMS);
    k_cvt<<<dim3(80, 5), 256, 0, stream>>>(W2, w2s);
    k_cvt<<<dim3(80, 5), 256, 0, stream>>>(W3, w3s);

    k_hihj<<<32, 512, 0, stream>>>(roi, b1, w1s, Hi, Hjb);
    k_g1<<<16 * 64, 512, 0, stream>>>(Hi, Hjb, b2, w2s, h2g);
    k_g2<<<16 * 64, 512, 0, stream>>>(h2g, b3, w3s, out);
}